// Round 6
// baseline (424.591 us; speedup 1.0000x reference)
//
#include <hip/hip_runtime.h>

#define N_NODES 10000
#define EDGES   160000
#define BATCH   8
#define TT      12
#define HID     64
#define EPAD    230000   // 160000 + 10000*7 worst-case pad-to-8

// ---------------- CSR build ----------------

__global__ __launch_bounds__(256) void k_cnt(const int* __restrict__ ei,
                                             int* __restrict__ cnt) {
  int g = blockIdx.x * 256 + threadIdx.x;
  if (g < EDGES) atomicAdd(&cnt[ei[EDGES + g]], 1);
}

// prefix scan of per-node counts PADDED UP TO MULTIPLE OF 8
__global__ __launch_bounds__(1024) void k_scan(const int* __restrict__ cnt,
                                               int* __restrict__ row_ptr,
                                               int* __restrict__ cursor) {
  __shared__ int part[1024];
  int tid = threadIdx.x;
  int base = tid * 10;
  int local[10];
  int s = 0;
  #pragma unroll
  for (int j = 0; j < 10; j++) {
    int idx = base + j;
    int v = (idx < N_NODES) ? cnt[idx] : 0;
    v = (v + 7) & ~7;              // pad each node's list to multiple of 8
    local[j] = s;
    s += v;
  }
  part[tid] = s;
  __syncthreads();
  for (int off = 1; off < 1024; off <<= 1) {
    int v = (tid >= off) ? part[tid - off] : 0;
    __syncthreads();
    part[tid] += v;
    __syncthreads();
  }
  int pre = (tid > 0) ? part[tid - 1] : 0;
  #pragma unroll
  for (int j = 0; j < 10; j++) {
    int idx = base + j;
    if (idx < N_NODES) {
      int rpv = pre + local[j];
      row_ptr[idx] = rpv;
      cursor[idx]  = rpv;
    }
  }
  if (tid == 0) row_ptr[N_NODES] = part[1023];
}

// fill CSR with raw weights (no dinv yet)
__global__ __launch_bounds__(256) void k_fill(const int* __restrict__ ei,
                                              const float* __restrict__ ew,
                                              int* __restrict__ cursor,
                                              int* __restrict__ csrc,
                                              float* __restrict__ cnorm) {
  int g = blockIdx.x * 256 + threadIdx.x;
  if (g < EDGES) {
    int s = ei[g], d = ei[EDGES + g];
    int slot = atomicAdd(&cursor[d], 1);
    csrc[slot]  = s;
    cnorm[slot] = ew[g];
  }
}

// fill pad slots (cursor[n]..rp[n+1]) with src=0, w=0
__global__ __launch_bounds__(256) void k_padfill(const int* __restrict__ rp,
                                                 const int* __restrict__ cursor,
                                                 int* __restrict__ csrc,
                                                 float* __restrict__ cnorm) {
  int n = blockIdx.x * 256 + threadIdx.x;
  if (n >= N_NODES) return;
  int e = cursor[n], e1 = rp[n + 1];
  for (; e < e1; e++) { csrc[e] = 0; cnorm[e] = 0.0f; }
}

// wave per node: deg = 1 + sum(raw w), dinv = deg^-0.5  (no float atomics)
__global__ __launch_bounds__(256) void k_degsum(const int* __restrict__ rp,
                                                const float* __restrict__ cnorm,
                                                float* __restrict__ dinv) {
  int n = blockIdx.x * 4 + (threadIdx.x >> 6);
  int lane = threadIdx.x & 63;
  int e0 = rp[n], e1 = rp[n + 1];
  float s = 0.0f;
  for (int e = e0 + lane; e < e1; e += 64) s += cnorm[e];
  #pragma unroll
  for (int off = 32; off > 0; off >>= 1) s += __shfl_xor(s, off, 64);
  if (lane == 0) dinv[n] = 1.0f / sqrtf(s + 1.0f);
}

// wave per node: cnorm[e] *= dinv[src]*dinv[n]
__global__ __launch_bounds__(256) void k_wnorm(const int* __restrict__ rp,
                                               const int* __restrict__ csrc,
                                               const float* __restrict__ dinv,
                                               float* __restrict__ cnorm) {
  int n = blockIdx.x * 4 + (threadIdx.x >> 6);
  int lane = threadIdx.x & 63;
  float dn = dinv[n];
  int e0 = rp[n], e1 = rp[n + 1];
  for (int e = e0 + lane; e < e1; e += 64)
    cnorm[e] = cnorm[e] * dinv[csrc[e]] * dn;
}

// pack conv weights:
//  p1c [192][128]: row kk: t3=kk>>6, i=kk&63; col: half=col>>6 (t'=10+half), o=col&63
//  p2c [128][64]:  row kk: g=kk>>6 (t1 half), i=kk&63
//  pb1 [128] = tc1_b duplicated
__global__ __launch_bounds__(256) void k_pack(const float* __restrict__ tc1w,
                                              const float* __restrict__ tc2w,
                                              const float* __restrict__ tc1b,
                                              float* __restrict__ p1c,
                                              float* __restrict__ p2c,
                                              float* __restrict__ pb1) {
  int g = blockIdx.x * 256 + threadIdx.x;
  if (g < 24576) {
    int kk = g >> 7, col = g & 127;
    int t3 = kk >> 6, i = kk & 63;
    int half = col >> 6, o = col & 63;
    float v;
    if (half == 0) v = tc1w[o * 192 + i * 3 + t3];
    else           v = (t3 == 0) ? 0.0f : tc1w[o * 192 + i * 3 + (t3 - 1)];
    p1c[g] = v;
  } else if (g < 24576 + 8192) {
    int r = g - 24576;
    int kk = r >> 6, o = r & 63;
    int gk = kk >> 6, i = kk & 63;
    p2c[r] = tc2w[o * 192 + i * 3 + gk];
  } else if (g < 24576 + 8192 + 128) {
    int r = g - 24576 - 8192;
    pb1[r] = tc1b[r & 63];
  }
}

// ---------------- GCN layer 1: fused agg(X) @ W1 + b1, relu -> h1[b][n][t3*64+c] ----------------

__global__ __launch_bounds__(256) void k_aggg1(const float* __restrict__ X,
                                               const float* __restrict__ dinv,
                                               const int* __restrict__ rp,
                                               const int* __restrict__ csrc,
                                               const float* __restrict__ cnorm,
                                               const float* __restrict__ W1,
                                               const float* __restrict__ b1,
                                               float* __restrict__ h1) {
  int b = blockIdx.x & 7;                    // batch -> XCD affinity
  int grp = blockIdx.x >> 3;                 // 0..2499
  int n = grp * 4 + (threadIdx.x >> 6);
  int lane = threadIdx.x & 63;
  const float2* x0 = (const float2*)(X + (size_t)(b * TT + 9)  * N_NODES * 2);
  const float2* x1 = (const float2*)(X + (size_t)(b * TT + 10) * N_NODES * 2);
  const float2* x2 = (const float2*)(X + (size_t)(b * TT + 11) * N_NODES * 2);
  float a0x = 0.f, a0y = 0.f, a1x = 0.f, a1y = 0.f, a2x = 0.f, a2y = 0.f;
  int e0 = rp[n], e1 = rp[n + 1];
  for (int idx = e0 + lane; idx < e1; idx += 64) {
    float w = cnorm[idx];
    int s = csrc[idx];
    float2 s0 = x0[s], s1 = x1[s], s2v = x2[s];
    a0x += w * s0.x;  a0y += w * s0.y;
    a1x += w * s1.x;  a1y += w * s1.y;
    a2x += w * s2v.x; a2y += w * s2v.y;
  }
  if (lane == 0) {  // self-loop term
    float di = dinv[n];
    float sd = di * di;
    float2 v0 = x0[n], v1 = x1[n], v2 = x2[n];
    a0x += sd * v0.x; a0y += sd * v0.y;
    a1x += sd * v1.x; a1y += sd * v1.y;
    a2x += sd * v2.x; a2y += sd * v2.y;
  }
  #pragma unroll
  for (int off = 32; off > 0; off >>= 1) {
    a0x += __shfl_xor(a0x, off, 64);
    a0y += __shfl_xor(a0y, off, 64);
    a1x += __shfl_xor(a1x, off, 64);
    a1y += __shfl_xor(a1y, off, 64);
    a2x += __shfl_xor(a2x, off, 64);
    a2y += __shfl_xor(a2y, off, 64);
  }
  int c = lane;
  float w0 = W1[c], w1 = W1[64 + c], bc = b1[c];
  size_t ob = ((size_t)(b * N_NODES + n)) * 192 + c;
  h1[ob]       = fmaxf(a0x * w0 + a0y * w1 + bc, 0.0f);
  h1[ob + 64]  = fmaxf(a1x * w0 + a1y * w1 + bc, 0.0f);
  h1[ob + 128] = fmaxf(a2x * w0 + a2y * w1 + bc, 0.0f);
}

// ---------------- GCN layer 2 aggregation: t3-sliced (L2-resident), 8 edges/iter ----
__global__ __launch_bounds__(256) void k_agg1t4(const float* __restrict__ h1,
                                                const float* __restrict__ dinv,
                                                const int* __restrict__ rp,
                                                const int* __restrict__ csrc,
                                                const float* __restrict__ cnorm,
                                                float* __restrict__ ah) {
  int b = blockIdx.x & 7;
  int r = blockIdx.x >> 3;                   // 0..7499
  int t3 = r / 2500;
  int grp = r % 2500;
  int n = grp * 4 + (threadIdx.x >> 6);
  int lane = threadIdx.x & 63;
  int sub = lane >> 4;
  int q = lane & 15;
  const char* plane = (const char*)(h1 + (size_t)b * N_NODES * 192 + t3 * 64);
  int qoff = q * 16;
  float ax = 0.f, ay = 0.f, az = 0.f, aw = 0.f;
  int e0 = rp[n], e1 = rp[n + 1];
  for (int base = e0; base < e1; base += 64) {
    int idx = base + lane;
    int ic = (idx < e1) ? idx : e0;
    int   sv = csrc[ic] * 768;               // pre-scaled row offset
    int   wv = ((const int*)cnorm)[ic];
    int m = e1 - base; if (m > 64) m = 64;   // multiple of 8 -> ng even
    int ng = m >> 2;
    int perm = sub * 4;
    for (int g2 = 0; g2 < ng; g2 += 2) {
      int   o0 = __builtin_amdgcn_ds_bpermute(perm, sv);
      float w0 = __int_as_float(__builtin_amdgcn_ds_bpermute(perm, wv));
      int   o1 = __builtin_amdgcn_ds_bpermute(perm + 16, sv);
      float w1 = __int_as_float(__builtin_amdgcn_ds_bpermute(perm + 16, wv));
      float4 h0 = *(const float4*)(plane + o0 + qoff);
      float4 h1v = *(const float4*)(plane + o1 + qoff);
      ax += w0 * h0.x;  ay += w0 * h0.y;  az += w0 * h0.z;  aw += w0 * h0.w;
      ax += w1 * h1v.x; ay += w1 * h1v.y; az += w1 * h1v.z; aw += w1 * h1v.w;
      perm += 32;
    }
  }
  // reduce across the 4 sub-groups
  ax += __shfl_xor(ax, 16, 64); ay += __shfl_xor(ay, 16, 64);
  az += __shfl_xor(az, 16, 64); aw += __shfl_xor(aw, 16, 64);
  ax += __shfl_xor(ax, 32, 64); ay += __shfl_xor(ay, 32, 64);
  az += __shfl_xor(az, 32, 64); aw += __shfl_xor(aw, 32, 64);
  if (sub == 0) {
    float di = dinv[n];
    float s2 = di * di;
    float4 self = *(const float4*)(plane + __mul24(n, 768) + qoff);
    float4 o;
    o.x = ax + s2 * self.x;
    o.y = ay + s2 * self.y;
    o.z = az + s2 * self.z;
    o.w = aw + s2 * self.w;
    *(float4*)((char*)ah + (((size_t)(b * N_NODES + n)) * 192 + t3 * 64) * 4 + qoff) = o;
  }
}

// ---------------- fused epilogue v3: 20 nodes/block, weights direct from global, 2 barriers ----
// LDS = spL[24][196] + t1L[24][132] = 31,488 B -> 5 blocks/CU.
__global__ __launch_bounds__(256, 5) void k_fused(const float* __restrict__ ah,
                                                  const float* __restrict__ W2,
                                                  const float* __restrict__ b2,
                                                  const float* __restrict__ p1c,
                                                  const float* __restrict__ pb1,
                                                  const float* __restrict__ p2c,
                                                  const float* __restrict__ tc2b,
                                                  const float* __restrict__ ow,
                                                  const float* __restrict__ obp,
                                                  float* __restrict__ out) {
  __shared__ __align__(16) float spL[24 * 196];  // [node][t3*64+c], rows 20..23 unused
  __shared__ __align__(16) float t1L[24 * 132];  // [node][col], rows 20..23 garbage
  int tid = threadIdx.x;
  size_t nodeBase = (size_t)blockIdx.x * 20;
  const float* A = ah + nodeBase * 192;          // 60 rows (n*3+t3) x 64

  // ---- phase 1: sp = relu(A[60x64] @ W2[64x64] + b2) -> spL
  {
    int ty = tid >> 4, tx = tid & 15;            // rows 4ty+i (ty<15), cols 4tx+j
    if (ty < 15) {
      float acc[4][4] = {{0.f}};
      const float* Ar = A + (4 * ty) * 64;
      #pragma unroll 2
      for (int k = 0; k < 64; k += 4) {
        float4 a[4], w[4];
        #pragma unroll
        for (int i = 0; i < 4; i++) a[i] = *(const float4*)(Ar + i * 64 + k);
        #pragma unroll
        for (int kk = 0; kk < 4; kk++) w[kk] = *(const float4*)(W2 + (k + kk) * 64 + 4 * tx);
        #pragma unroll
        for (int i = 0; i < 4; i++) {
          float av[4] = {a[i].x, a[i].y, a[i].z, a[i].w};
          #pragma unroll
          for (int kk = 0; kk < 4; kk++) {
            acc[i][0] += av[kk] * w[kk].x;
            acc[i][1] += av[kk] * w[kk].y;
            acc[i][2] += av[kk] * w[kk].z;
            acc[i][3] += av[kk] * w[kk].w;
          }
        }
      }
      float4 bv = *(const float4*)(b2 + 4 * tx);
      #pragma unroll
      for (int i = 0; i < 4; i++) {
        int m = 4 * ty + i;
        int nn = m / 3, t3 = m % 3;
        float4 o;
        o.x = fmaxf(acc[i][0] + bv.x, 0.0f);
        o.y = fmaxf(acc[i][1] + bv.y, 0.0f);
        o.z = fmaxf(acc[i][2] + bv.z, 0.0f);
        o.w = fmaxf(acc[i][3] + bv.w, 0.0f);
        *(float4*)&spL[nn * 196 + t3 * 64 + 4 * tx] = o;
      }
    }
  }
  __syncthreads();

  // ---- phase 2: t1 = relu(spL[20x192] @ p1c[192x128] + pb1) -> t1L (rows 20..23 garbage)
  {
    int ty = tid >> 5, tx = tid & 31;            // rows 3ty+i, cols 4tx+j
    float acc[3][4] = {{0.f}};
    #pragma unroll 2
    for (int k = 0; k < 192; k += 4) {
      float4 a[3], w[4];
      #pragma unroll
      for (int i = 0; i < 3; i++) a[i] = *(const float4*)&spL[(3 * ty + i) * 196 + k];
      #pragma unroll
      for (int kk = 0; kk < 4; kk++) w[kk] = *(const float4*)(p1c + (k + kk) * 128 + 4 * tx);
      #pragma unroll
      for (int i = 0; i < 3; i++) {
        float av[4] = {a[i].x, a[i].y, a[i].z, a[i].w};
        #pragma unroll
        for (int kk = 0; kk < 4; kk++) {
          acc[i][0] += av[kk] * w[kk].x;
          acc[i][1] += av[kk] * w[kk].y;
          acc[i][2] += av[kk] * w[kk].z;
          acc[i][3] += av[kk] * w[kk].w;
        }
      }
    }
    float4 bv = *(const float4*)(pb1 + 4 * tx);
    #pragma unroll
    for (int i = 0; i < 3; i++) {
      float4 o;
      o.x = fmaxf(acc[i][0] + bv.x, 0.0f);
      o.y = fmaxf(acc[i][1] + bv.y, 0.0f);
      o.z = fmaxf(acc[i][2] + bv.z, 0.0f);
      o.w = fmaxf(acc[i][3] + bv.w, 0.0f);
      *(float4*)&t1L[(3 * ty + i) * 132 + 4 * tx] = o;
    }
  }
  __syncthreads();

  // ---- phase 3: last = relu(t1L[20x128] @ p2c[128x64] + tc2b); out = last . ow + ob
  {
    int ty = tid >> 4, tx = tid & 15;            // rows 2ty+i (ty<10), cols 4tx+j
    if (ty < 10) {
      float acc[2][4] = {{0.f}};
      #pragma unroll 2
      for (int k = 0; k < 128; k += 4) {
        float4 a[2], w[4];
        #pragma unroll
        for (int i = 0; i < 2; i++) a[i] = *(const float4*)&t1L[(2 * ty + i) * 132 + k];
        #pragma unroll
        for (int kk = 0; kk < 4; kk++) w[kk] = *(const float4*)(p2c + (k + kk) * 64 + 4 * tx);
        #pragma unroll
        for (int i = 0; i < 2; i++) {
          float av[4] = {a[i].x, a[i].y, a[i].z, a[i].w};
          #pragma unroll
          for (int kk = 0; kk < 4; kk++) {
            acc[i][0] += av[kk] * w[kk].x;
            acc[i][1] += av[kk] * w[kk].y;
            acc[i][2] += av[kk] * w[kk].z;
            acc[i][3] += av[kk] * w[kk].w;
          }
        }
      }
      float4 bv = *(const float4*)(tc2b + 4 * tx);
      float4 o4 = *(const float4*)(ow + 4 * tx);
      float obv = obp[0];
      #pragma unroll
      for (int i = 0; i < 2; i++) {
        float v = fmaxf(acc[i][0] + bv.x, 0.0f) * o4.x
                + fmaxf(acc[i][1] + bv.y, 0.0f) * o4.y
                + fmaxf(acc[i][2] + bv.z, 0.0f) * o4.z
                + fmaxf(acc[i][3] + bv.w, 0.0f) * o4.w;
        v += __shfl_xor(v, 1, 64);
        v += __shfl_xor(v, 2, 64);
        v += __shfl_xor(v, 4, 64);
        v += __shfl_xor(v, 8, 64);
        if (tx == 0) out[nodeBase + 2 * ty + i] = v + obv;
      }
    }
  }
}

// ---------------- launch ----------------

extern "C" void kernel_launch(void* const* d_in, const int* in_sizes, int n_in,
                              void* d_out, int out_size, void* d_ws, size_t ws_size,
                              hipStream_t stream) {
  const float* X    = (const float*)d_in[0];
  const int*   EI   = (const int*)  d_in[1];
  const float* EW   = (const float*)d_in[2];
  const float* W1   = (const float*)d_in[3];
  const float* B1   = (const float*)d_in[4];
  const float* W2   = (const float*)d_in[5];
  const float* B2   = (const float*)d_in[6];
  const float* TC1W = (const float*)d_in[7];
  const float* TC1B = (const float*)d_in[8];
  const float* TC2W = (const float*)d_in[9];
  const float* TC2B = (const float*)d_in[10];
  const float* OW   = (const float*)d_in[11];
  const float* OB   = (const float*)d_in[12];
  float* out = (float*)d_out;

  char* base = (char*)d_ws;
  size_t off = 0;
  auto alloc = [&](size_t bytes) -> char* {
    char* p = base + off;
    off += (bytes + 255) & ~(size_t)255;
    return p;
  };
  float* dinv  = (float*)alloc(N_NODES * 4);
  int*   cnt   = (int*)  alloc(N_NODES * 4);
  int*   rp    = (int*)  alloc((N_NODES + 1) * 4);
  int*   cur   = (int*)  alloc(N_NODES * 4);
  int*   csrc  = (int*)  alloc(EPAD * 4);
  float* cnorm = (float*)alloc(EPAD * 4);
  float* p1c   = (float*)alloc(192 * 128 * 4);
  float* p2c   = (float*)alloc(128 * 64 * 4);
  float* pb1   = (float*)alloc(128 * 4);
  const size_t BIG = (size_t)80000 * 192;
  float* h1 = (float*)alloc(BIG * 4);
  float* ah = (float*)alloc(BIG * 4);

  hipMemsetAsync(cnt, 0, N_NODES * 4, stream);
  k_cnt<<<625, 256, 0, stream>>>(EI, cnt);
  k_scan<<<1, 1024, 0, stream>>>(cnt, rp, cur);
  k_fill<<<625, 256, 0, stream>>>(EI, EW, cur, csrc, cnorm);
  k_padfill<<<40, 256, 0, stream>>>(rp, cur, csrc, cnorm);
  k_degsum<<<2500, 256, 0, stream>>>(rp, cnorm, dinv);
  k_wnorm<<<2500, 256, 0, stream>>>(rp, csrc, dinv, cnorm);
  k_pack<<<129, 256, 0, stream>>>(TC1W, TC2W, TC1B, p1c, p2c, pb1);

  // layer 1 (agg + W1 + relu), t=9..11 fused
  k_aggg1<<<20000, 256, 0, stream>>>(X, dinv, rp, csrc, cnorm, W1, B1, h1);
  // layer 2 aggregation, t3-sliced, 8-edge vector gather
  k_agg1t4<<<60000, 256, 0, stream>>>(h1, dinv, rp, csrc, cnorm, ah);
  // fused W2-GEMM + conv1 + conv2 + out (20 nodes/block, 2 barriers)
  k_fused<<<4000, 256, 0, stream>>>(ah, W2, B2, p1c, pb1, p2c, TC2B, OW, OB, out);
}

// Round 7
// 419.572 us; speedup vs baseline: 1.0120x; 1.0120x over previous
//
#include <hip/hip_runtime.h>

#define N_NODES 10000
#define EDGES   160000
#define BATCH   8
#define TT      12
#define HID     64
#define EPAD    230000   // 160000 + 10000*7 worst-case pad-to-8

// ---------------- CSR build ----------------

__global__ __launch_bounds__(256) void k_cnt(const int* __restrict__ ei,
                                             int* __restrict__ cnt) {
  int g = blockIdx.x * 256 + threadIdx.x;
  if (g < EDGES) atomicAdd(&cnt[ei[EDGES + g]], 1);
}

// prefix scan of per-node counts PADDED UP TO MULTIPLE OF 8
__global__ __launch_bounds__(1024) void k_scan(const int* __restrict__ cnt,
                                               int* __restrict__ row_ptr,
                                               int* __restrict__ cursor) {
  __shared__ int part[1024];
  int tid = threadIdx.x;
  int base = tid * 10;
  int local[10];
  int s = 0;
  #pragma unroll
  for (int j = 0; j < 10; j++) {
    int idx = base + j;
    int v = (idx < N_NODES) ? cnt[idx] : 0;
    v = (v + 7) & ~7;              // pad each node's list to multiple of 8
    local[j] = s;
    s += v;
  }
  part[tid] = s;
  __syncthreads();
  for (int off = 1; off < 1024; off <<= 1) {
    int v = (tid >= off) ? part[tid - off] : 0;
    __syncthreads();
    part[tid] += v;
    __syncthreads();
  }
  int pre = (tid > 0) ? part[tid - 1] : 0;
  #pragma unroll
  for (int j = 0; j < 10; j++) {
    int idx = base + j;
    if (idx < N_NODES) {
      int rpv = pre + local[j];
      row_ptr[idx] = rpv;
      cursor[idx]  = rpv;
    }
  }
  if (tid == 0) row_ptr[N_NODES] = part[1023];
}

// fill CSR with raw weights (no dinv yet)
__global__ __launch_bounds__(256) void k_fill(const int* __restrict__ ei,
                                              const float* __restrict__ ew,
                                              int* __restrict__ cursor,
                                              int* __restrict__ csrc,
                                              float* __restrict__ cnorm) {
  int g = blockIdx.x * 256 + threadIdx.x;
  if (g < EDGES) {
    int s = ei[g], d = ei[EDGES + g];
    int slot = atomicAdd(&cursor[d], 1);
    csrc[slot]  = s;
    cnorm[slot] = ew[g];
  }
}

// fill pad slots (cursor[n]..rp[n+1]) with src=0, w=0
__global__ __launch_bounds__(256) void k_padfill(const int* __restrict__ rp,
                                                 const int* __restrict__ cursor,
                                                 int* __restrict__ csrc,
                                                 float* __restrict__ cnorm) {
  int n = blockIdx.x * 256 + threadIdx.x;
  if (n >= N_NODES) return;
  int e = cursor[n], e1 = rp[n + 1];
  for (; e < e1; e++) { csrc[e] = 0; cnorm[e] = 0.0f; }
}

// wave per node: deg = 1 + sum(raw w), dinv = deg^-0.5  (no float atomics)
__global__ __launch_bounds__(256) void k_degsum(const int* __restrict__ rp,
                                                const float* __restrict__ cnorm,
                                                float* __restrict__ dinv) {
  int n = blockIdx.x * 4 + (threadIdx.x >> 6);
  int lane = threadIdx.x & 63;
  int e0 = rp[n], e1 = rp[n + 1];
  float s = 0.0f;
  for (int e = e0 + lane; e < e1; e += 64) s += cnorm[e];
  #pragma unroll
  for (int off = 32; off > 0; off >>= 1) s += __shfl_xor(s, off, 64);
  if (lane == 0) dinv[n] = 1.0f / sqrtf(s + 1.0f);
}

// wave per node: cnorm[e] *= dinv[src]*dinv[n]
__global__ __launch_bounds__(256) void k_wnorm(const int* __restrict__ rp,
                                               const int* __restrict__ csrc,
                                               const float* __restrict__ dinv,
                                               float* __restrict__ cnorm) {
  int n = blockIdx.x * 4 + (threadIdx.x >> 6);
  int lane = threadIdx.x & 63;
  float dn = dinv[n];
  int e0 = rp[n], e1 = rp[n + 1];
  for (int e = e0 + lane; e < e1; e += 64)
    cnorm[e] = cnorm[e] * dinv[csrc[e]] * dn;
}

// pack conv weights:
//  p1c [192][128]: row kk: t3=kk>>6, i=kk&63; col: half=col>>6 (t'=10+half), o=col&63
//  p2c [128][64]:  row kk: g=kk>>6 (t1 half), i=kk&63
//  pb1 [128] = tc1_b duplicated
__global__ __launch_bounds__(256) void k_pack(const float* __restrict__ tc1w,
                                              const float* __restrict__ tc2w,
                                              const float* __restrict__ tc1b,
                                              float* __restrict__ p1c,
                                              float* __restrict__ p2c,
                                              float* __restrict__ pb1) {
  int g = blockIdx.x * 256 + threadIdx.x;
  if (g < 24576) {
    int kk = g >> 7, col = g & 127;
    int t3 = kk >> 6, i = kk & 63;
    int half = col >> 6, o = col & 63;
    float v;
    if (half == 0) v = tc1w[o * 192 + i * 3 + t3];
    else           v = (t3 == 0) ? 0.0f : tc1w[o * 192 + i * 3 + (t3 - 1)];
    p1c[g] = v;
  } else if (g < 24576 + 8192) {
    int r = g - 24576;
    int kk = r >> 6, o = r & 63;
    int gk = kk >> 6, i = kk & 63;
    p2c[r] = tc2w[o * 192 + i * 3 + gk];
  } else if (g < 24576 + 8192 + 128) {
    int r = g - 24576 - 8192;
    pb1[r] = tc1b[r & 63];
  }
}

// ---------------- GCN layer 1: fused agg(X) @ W1 + b1, relu -> h1[b][n][t3*64+c] ----------------

__global__ __launch_bounds__(256) void k_aggg1(const float* __restrict__ X,
                                               const float* __restrict__ dinv,
                                               const int* __restrict__ rp,
                                               const int* __restrict__ csrc,
                                               const float* __restrict__ cnorm,
                                               const float* __restrict__ W1,
                                               const float* __restrict__ b1,
                                               float* __restrict__ h1) {
  int b = blockIdx.x & 7;                    // batch -> XCD affinity
  int grp = blockIdx.x >> 3;                 // 0..2499
  int n = grp * 4 + (threadIdx.x >> 6);
  int lane = threadIdx.x & 63;
  const float2* x0 = (const float2*)(X + (size_t)(b * TT + 9)  * N_NODES * 2);
  const float2* x1 = (const float2*)(X + (size_t)(b * TT + 10) * N_NODES * 2);
  const float2* x2 = (const float2*)(X + (size_t)(b * TT + 11) * N_NODES * 2);
  float a0x = 0.f, a0y = 0.f, a1x = 0.f, a1y = 0.f, a2x = 0.f, a2y = 0.f;
  int e0 = rp[n], e1 = rp[n + 1];
  for (int idx = e0 + lane; idx < e1; idx += 64) {
    float w = cnorm[idx];
    int s = csrc[idx];
    float2 s0 = x0[s], s1 = x1[s], s2v = x2[s];
    a0x += w * s0.x;  a0y += w * s0.y;
    a1x += w * s1.x;  a1y += w * s1.y;
    a2x += w * s2v.x; a2y += w * s2v.y;
  }
  if (lane == 0) {  // self-loop term
    float di = dinv[n];
    float sd = di * di;
    float2 v0 = x0[n], v1 = x1[n], v2 = x2[n];
    a0x += sd * v0.x; a0y += sd * v0.y;
    a1x += sd * v1.x; a1y += sd * v1.y;
    a2x += sd * v2.x; a2y += sd * v2.y;
  }
  #pragma unroll
  for (int off = 32; off > 0; off >>= 1) {
    a0x += __shfl_xor(a0x, off, 64);
    a0y += __shfl_xor(a0y, off, 64);
    a1x += __shfl_xor(a1x, off, 64);
    a1y += __shfl_xor(a1y, off, 64);
    a2x += __shfl_xor(a2x, off, 64);
    a2y += __shfl_xor(a2y, off, 64);
  }
  int c = lane;
  float w0 = W1[c], w1 = W1[64 + c], bc = b1[c];
  size_t ob = ((size_t)(b * N_NODES + n)) * 192 + c;
  h1[ob]       = fmaxf(a0x * w0 + a0y * w1 + bc, 0.0f);
  h1[ob + 64]  = fmaxf(a1x * w0 + a1y * w1 + bc, 0.0f);
  h1[ob + 128] = fmaxf(a2x * w0 + a2y * w1 + bc, 0.0f);
}

// ---------------- GCN layer 2 aggregation: t3-sliced (L2-resident), 8 edges/iter ----
__global__ __launch_bounds__(256) void k_agg1t4(const float* __restrict__ h1,
                                                const float* __restrict__ dinv,
                                                const int* __restrict__ rp,
                                                const int* __restrict__ csrc,
                                                const float* __restrict__ cnorm,
                                                float* __restrict__ ah) {
  int b = blockIdx.x & 7;
  int r = blockIdx.x >> 3;                   // 0..7499
  int t3 = r / 2500;
  int grp = r % 2500;
  int n = grp * 4 + (threadIdx.x >> 6);
  int lane = threadIdx.x & 63;
  int sub = lane >> 4;
  int q = lane & 15;
  const char* plane = (const char*)(h1 + (size_t)b * N_NODES * 192 + t3 * 64);
  int qoff = q * 16;
  float ax = 0.f, ay = 0.f, az = 0.f, aw = 0.f;
  int e0 = rp[n], e1 = rp[n + 1];
  for (int base = e0; base < e1; base += 64) {
    int idx = base + lane;
    int ic = (idx < e1) ? idx : e0;
    int   sv = csrc[ic] * 768;               // pre-scaled row offset
    int   wv = ((const int*)cnorm)[ic];
    int m = e1 - base; if (m > 64) m = 64;   // multiple of 8 -> ng even
    int ng = m >> 2;
    int perm = sub * 4;
    for (int g2 = 0; g2 < ng; g2 += 2) {
      int   o0 = __builtin_amdgcn_ds_bpermute(perm, sv);
      float w0 = __int_as_float(__builtin_amdgcn_ds_bpermute(perm, wv));
      int   o1 = __builtin_amdgcn_ds_bpermute(perm + 16, sv);
      float w1 = __int_as_float(__builtin_amdgcn_ds_bpermute(perm + 16, wv));
      float4 h0 = *(const float4*)(plane + o0 + qoff);
      float4 h1v = *(const float4*)(plane + o1 + qoff);
      ax += w0 * h0.x;  ay += w0 * h0.y;  az += w0 * h0.z;  aw += w0 * h0.w;
      ax += w1 * h1v.x; ay += w1 * h1v.y; az += w1 * h1v.z; aw += w1 * h1v.w;
      perm += 32;
    }
  }
  // reduce across the 4 sub-groups
  ax += __shfl_xor(ax, 16, 64); ay += __shfl_xor(ay, 16, 64);
  az += __shfl_xor(az, 16, 64); aw += __shfl_xor(aw, 16, 64);
  ax += __shfl_xor(ax, 32, 64); ay += __shfl_xor(ay, 32, 64);
  az += __shfl_xor(az, 32, 64); aw += __shfl_xor(aw, 32, 64);
  if (sub == 0) {
    float di = dinv[n];
    float s2 = di * di;
    float4 self = *(const float4*)(plane + __mul24(n, 768) + qoff);
    float4 o;
    o.x = ax + s2 * self.x;
    o.y = ay + s2 * self.y;
    o.z = az + s2 * self.z;
    o.w = aw + s2 * self.w;
    *(float4*)((char*)ah + (((size_t)(b * N_NODES + n)) * 192 + t3 * 64) * 4 + qoff) = o;
  }
}

// ---------------- fused epilogue v4: row-stationary, scalar-uniform weights, 3 barriers ----
// 64 nodes/block, 512 threads (8 waves), grid 1250. LDS = spL[64][193] + t1L[64][129] = 82,432 B.
// lane = output row; wave = 8-16 output cols; weights via readfirstlane -> s_load (SMEM broadcast).
__global__ __launch_bounds__(512, 1) void k_fused(const float* __restrict__ ah,
                                                  const float* __restrict__ W2,
                                                  const float* __restrict__ b2,
                                                  const float* __restrict__ p1c,
                                                  const float* __restrict__ pb1,
                                                  const float* __restrict__ p2c,
                                                  const float* __restrict__ tc2b,
                                                  const float* __restrict__ ow,
                                                  const float* __restrict__ obp,
                                                  float* __restrict__ out) {
  __shared__ __align__(16) float spL[64 * 193];  // [node][t3*64+c], stride 193 (==1 mod 32)
  __shared__ __align__(16) float t1L[64 * 129];  // [node][col], stride 129
  float* pmem = spL;                             // [64][8] partials overlay (after phase 2)
  int lane = threadIdx.x & 63;
  int wid  = __builtin_amdgcn_readfirstlane(threadIdx.x >> 6);  // 0..7, SGPR
  size_t nodeBase = (size_t)blockIdx.x * 64;
  const float* A = ah + nodeBase * 192;          // viewed as [192 rows = 3n+t3][64]

  // ---- phase 1: sp = relu(A[192x64] @ W2[64x64] + b2) -> spL
  {
    const float* Wp = W2 + wid * 8;              // uniform col base
    const float* Ar = A + lane * 64;             // rows lane, lane+64, lane+128
    float acc[3][8] = {{0.f}};
    #pragma unroll 4
    for (int k4 = 0; k4 < 16; k4++) {
      float4 a0 = *(const float4*)(Ar + k4 * 4);
      float4 a1 = *(const float4*)(Ar + 64 * 64 + k4 * 4);
      float4 a2 = *(const float4*)(Ar + 128 * 64 + k4 * 4);
      float av[3][4] = {{a0.x, a0.y, a0.z, a0.w},
                        {a1.x, a1.y, a1.z, a1.w},
                        {a2.x, a2.y, a2.z, a2.w}};
      #pragma unroll
      for (int kk = 0; kk < 4; kk++) {
        float4 w0 = *(const float4*)(Wp + (k4 * 4 + kk) * 64);
        float4 w1 = *(const float4*)(Wp + (k4 * 4 + kk) * 64 + 4);
        float w[8] = {w0.x, w0.y, w0.z, w0.w, w1.x, w1.y, w1.z, w1.w};
        #pragma unroll
        for (int c = 0; c < 3; c++)
          #pragma unroll
          for (int j = 0; j < 8; j++)
            acc[c][j] += av[c][kk] * w[j];
      }
    }
    float bb[8];
    #pragma unroll
    for (int j = 0; j < 8; j++) bb[j] = b2[wid * 8 + j];
    #pragma unroll
    for (int c = 0; c < 3; c++) {
      int row = c * 64 + lane;
      int nn = row / 3, t3 = row - nn * 3;
      float* dst = &spL[nn * 193 + t3 * 64 + wid * 8];
      #pragma unroll
      for (int j = 0; j < 8; j++) dst[j] = fmaxf(acc[c][j] + bb[j], 0.0f);
    }
  }
  __syncthreads();

  // ---- phase 2: t1 = relu(spL[64x192] @ p1c[192x128] + pb1) -> t1L
  {
    int wc = wid * 16;                           // uniform col base 0..112
    const float* Wp = p1c + wc;
    int kbeg = (wc >= 64) ? 64 : 0;              // t'=11 half: t3=0 rows are zero
    float acc[16] = {0.f};
    const float* arow = &spL[lane * 193];
    #pragma unroll 2
    for (int k = kbeg; k < 192; k++) {
      float a = arow[k];
      float4 w0 = *(const float4*)(Wp + k * 128);
      float4 w1 = *(const float4*)(Wp + k * 128 + 4);
      float4 w2 = *(const float4*)(Wp + k * 128 + 8);
      float4 w3 = *(const float4*)(Wp + k * 128 + 12);
      acc[0]  += a * w0.x; acc[1]  += a * w0.y; acc[2]  += a * w0.z; acc[3]  += a * w0.w;
      acc[4]  += a * w1.x; acc[5]  += a * w1.y; acc[6]  += a * w1.z; acc[7]  += a * w1.w;
      acc[8]  += a * w2.x; acc[9]  += a * w2.y; acc[10] += a * w2.z; acc[11] += a * w2.w;
      acc[12] += a * w3.x; acc[13] += a * w3.y; acc[14] += a * w3.z; acc[15] += a * w3.w;
    }
    float* dst = &t1L[lane * 129 + wc];
    #pragma unroll
    for (int j = 0; j < 16; j++) dst[j] = fmaxf(acc[j] + pb1[wc + j], 0.0f);
  }
  __syncthreads();

  // ---- phase 3: last = relu(t1L[64x128] @ p2c[128x64] + tc2b); out = last . ow + ob
  {
    int wc = wid * 8;
    const float* Wp = p2c + wc;
    float acc[8] = {0.f};
    const float* arow = &t1L[lane * 129];
    #pragma unroll 2
    for (int k = 0; k < 128; k++) {
      float a = arow[k];
      float4 w0 = *(const float4*)(Wp + k * 64);
      float4 w1 = *(const float4*)(Wp + k * 64 + 4);
      acc[0] += a * w0.x; acc[1] += a * w0.y; acc[2] += a * w0.z; acc[3] += a * w0.w;
      acc[4] += a * w1.x; acc[5] += a * w1.y; acc[6] += a * w1.z; acc[7] += a * w1.w;
    }
    float p = 0.0f;
    #pragma unroll
    for (int j = 0; j < 8; j++)
      p += fmaxf(acc[j] + tc2b[wc + j], 0.0f) * ow[wc + j];
    pmem[lane * 8 + wid] = p;
  }
  __syncthreads();
  if (wid == 0) {
    float s = 0.0f;
    #pragma unroll
    for (int w = 0; w < 8; w++) s += pmem[lane * 8 + w];
    out[nodeBase + lane] = s + obp[0];
  }
}

// ---------------- launch ----------------

extern "C" void kernel_launch(void* const* d_in, const int* in_sizes, int n_in,
                              void* d_out, int out_size, void* d_ws, size_t ws_size,
                              hipStream_t stream) {
  const float* X    = (const float*)d_in[0];
  const int*   EI   = (const int*)  d_in[1];
  const float* EW   = (const float*)d_in[2];
  const float* W1   = (const float*)d_in[3];
  const float* B1   = (const float*)d_in[4];
  const float* W2   = (const float*)d_in[5];
  const float* B2   = (const float*)d_in[6];
  const float* TC1W = (const float*)d_in[7];
  const float* TC1B = (const float*)d_in[8];
  const float* TC2W = (const float*)d_in[9];
  const float* TC2B = (const float*)d_in[10];
  const float* OW   = (const float*)d_in[11];
  const float* OB   = (const float*)d_in[12];
  float* out = (float*)d_out;

  char* base = (char*)d_ws;
  size_t off = 0;
  auto alloc = [&](size_t bytes) -> char* {
    char* p = base + off;
    off += (bytes + 255) & ~(size_t)255;
    return p;
  };
  float* dinv  = (float*)alloc(N_NODES * 4);
  int*   cnt   = (int*)  alloc(N_NODES * 4);
  int*   rp    = (int*)  alloc((N_NODES + 1) * 4);
  int*   cur   = (int*)  alloc(N_NODES * 4);
  int*   csrc  = (int*)  alloc(EPAD * 4);
  float* cnorm = (float*)alloc(EPAD * 4);
  float* p1c   = (float*)alloc(192 * 128 * 4);
  float* p2c   = (float*)alloc(128 * 64 * 4);
  float* pb1   = (float*)alloc(128 * 4);
  const size_t BIG = (size_t)80000 * 192;
  float* h1 = (float*)alloc(BIG * 4);
  float* ah = (float*)alloc(BIG * 4);

  hipMemsetAsync(cnt, 0, N_NODES * 4, stream);
  k_cnt<<<625, 256, 0, stream>>>(EI, cnt);
  k_scan<<<1, 1024, 0, stream>>>(cnt, rp, cur);
  k_fill<<<625, 256, 0, stream>>>(EI, EW, cur, csrc, cnorm);
  k_padfill<<<40, 256, 0, stream>>>(rp, cur, csrc, cnorm);
  k_degsum<<<2500, 256, 0, stream>>>(rp, cnorm, dinv);
  k_wnorm<<<2500, 256, 0, stream>>>(rp, csrc, dinv, cnorm);
  k_pack<<<129, 256, 0, stream>>>(TC1W, TC2W, TC1B, p1c, p2c, pb1);

  // layer 1 (agg + W1 + relu), t=9..11 fused
  k_aggg1<<<20000, 256, 0, stream>>>(X, dinv, rp, csrc, cnorm, W1, B1, h1);
  // layer 2 aggregation, t3-sliced, 8-edge vector gather
  k_agg1t4<<<60000, 256, 0, stream>>>(h1, dinv, rp, csrc, cnorm, ah);
  // fused W2-GEMM + conv1 + conv2 + out (64 nodes/block, scalar weights, 3 barriers)
  k_fused<<<1250, 512, 0, stream>>>(ah, W2, B2, p1c, pb1, p2c, TC2B, OW, OB, out);
}

// Round 8
// 359.174 us; speedup vs baseline: 1.1821x; 1.1682x over previous
//
#include <hip/hip_runtime.h>

#define N_NODES 10000
#define EDGES   160000
#define BATCH   8
#define TT      12
#define HID     64
#define EPAD    230000   // 160000 + 10000*7 worst-case pad-to-8

// ---------------- CSR build ----------------

__global__ __launch_bounds__(256) void k_cnt(const int* __restrict__ ei,
                                             int* __restrict__ cnt) {
  int g = blockIdx.x * 256 + threadIdx.x;
  if (g < EDGES) atomicAdd(&cnt[ei[EDGES + g]], 1);
}

// prefix scan of per-node counts PADDED UP TO MULTIPLE OF 8
__global__ __launch_bounds__(1024) void k_scan(const int* __restrict__ cnt,
                                               int* __restrict__ row_ptr,
                                               int* __restrict__ cursor) {
  __shared__ int part[1024];
  int tid = threadIdx.x;
  int base = tid * 10;
  int local[10];
  int s = 0;
  #pragma unroll
  for (int j = 0; j < 10; j++) {
    int idx = base + j;
    int v = (idx < N_NODES) ? cnt[idx] : 0;
    v = (v + 7) & ~7;              // pad each node's list to multiple of 8
    local[j] = s;
    s += v;
  }
  part[tid] = s;
  __syncthreads();
  for (int off = 1; off < 1024; off <<= 1) {
    int v = (tid >= off) ? part[tid - off] : 0;
    __syncthreads();
    part[tid] += v;
    __syncthreads();
  }
  int pre = (tid > 0) ? part[tid - 1] : 0;
  #pragma unroll
  for (int j = 0; j < 10; j++) {
    int idx = base + j;
    if (idx < N_NODES) {
      int rpv = pre + local[j];
      row_ptr[idx] = rpv;
      cursor[idx]  = rpv;
    }
  }
  if (tid == 0) row_ptr[N_NODES] = part[1023];
}

// fill CSR with raw weights (no dinv yet)
__global__ __launch_bounds__(256) void k_fill(const int* __restrict__ ei,
                                              const float* __restrict__ ew,
                                              int* __restrict__ cursor,
                                              int* __restrict__ csrc,
                                              float* __restrict__ cnorm) {
  int g = blockIdx.x * 256 + threadIdx.x;
  if (g < EDGES) {
    int s = ei[g], d = ei[EDGES + g];
    int slot = atomicAdd(&cursor[d], 1);
    csrc[slot]  = s;
    cnorm[slot] = ew[g];
  }
}

// fill pad slots (cursor[n]..rp[n+1]) with src=0, w=0
__global__ __launch_bounds__(256) void k_padfill(const int* __restrict__ rp,
                                                 const int* __restrict__ cursor,
                                                 int* __restrict__ csrc,
                                                 float* __restrict__ cnorm) {
  int n = blockIdx.x * 256 + threadIdx.x;
  if (n >= N_NODES) return;
  int e = cursor[n], e1 = rp[n + 1];
  for (; e < e1; e++) { csrc[e] = 0; cnorm[e] = 0.0f; }
}

// wave per node: deg = 1 + sum(raw w), dinv = deg^-0.5  (no float atomics)
__global__ __launch_bounds__(256) void k_degsum(const int* __restrict__ rp,
                                                const float* __restrict__ cnorm,
                                                float* __restrict__ dinv) {
  int n = blockIdx.x * 4 + (threadIdx.x >> 6);
  int lane = threadIdx.x & 63;
  int e0 = rp[n], e1 = rp[n + 1];
  float s = 0.0f;
  for (int e = e0 + lane; e < e1; e += 64) s += cnorm[e];
  #pragma unroll
  for (int off = 32; off > 0; off >>= 1) s += __shfl_xor(s, off, 64);
  if (lane == 0) dinv[n] = 1.0f / sqrtf(s + 1.0f);
}

// wave per node: cnorm[e] *= dinv[src]*dinv[n]
__global__ __launch_bounds__(256) void k_wnorm(const int* __restrict__ rp,
                                               const int* __restrict__ csrc,
                                               const float* __restrict__ dinv,
                                               float* __restrict__ cnorm) {
  int n = blockIdx.x * 4 + (threadIdx.x >> 6);
  int lane = threadIdx.x & 63;
  float dn = dinv[n];
  int e0 = rp[n], e1 = rp[n + 1];
  for (int e = e0 + lane; e < e1; e += 64)
    cnorm[e] = cnorm[e] * dinv[csrc[e]] * dn;
}

// pack conv weights:
//  p1c [192][128]: row kk: t3=kk>>6, i=kk&63; col: half=col>>6 (t'=10+half), o=col&63
//  p2c [128][64]:  row kk: g=kk>>6 (t1 half), i=kk&63
//  pb1 [128] = tc1_b duplicated
__global__ __launch_bounds__(256) void k_pack(const float* __restrict__ tc1w,
                                              const float* __restrict__ tc2w,
                                              const float* __restrict__ tc1b,
                                              float* __restrict__ p1c,
                                              float* __restrict__ p2c,
                                              float* __restrict__ pb1) {
  int g = blockIdx.x * 256 + threadIdx.x;
  if (g < 24576) {
    int kk = g >> 7, col = g & 127;
    int t3 = kk >> 6, i = kk & 63;
    int half = col >> 6, o = col & 63;
    float v;
    if (half == 0) v = tc1w[o * 192 + i * 3 + t3];
    else           v = (t3 == 0) ? 0.0f : tc1w[o * 192 + i * 3 + (t3 - 1)];
    p1c[g] = v;
  } else if (g < 24576 + 8192) {
    int r = g - 24576;
    int kk = r >> 6, o = r & 63;
    int gk = kk >> 6, i = kk & 63;
    p2c[r] = tc2w[o * 192 + i * 3 + gk];
  } else if (g < 24576 + 8192 + 128) {
    int r = g - 24576 - 8192;
    pb1[r] = tc1b[r & 63];
  }
}

// ---------------- GCN layer 1: fused agg(X) @ W1 + b1, relu -> h1[b][n][t3*64+c] ----------------

__global__ __launch_bounds__(256) void k_aggg1(const float* __restrict__ X,
                                               const float* __restrict__ dinv,
                                               const int* __restrict__ rp,
                                               const int* __restrict__ csrc,
                                               const float* __restrict__ cnorm,
                                               const float* __restrict__ W1,
                                               const float* __restrict__ b1,
                                               float* __restrict__ h1) {
  int b = blockIdx.x & 7;                    // batch -> XCD affinity
  int grp = blockIdx.x >> 3;                 // 0..2499
  int n = grp * 4 + (threadIdx.x >> 6);
  int lane = threadIdx.x & 63;
  const float2* x0 = (const float2*)(X + (size_t)(b * TT + 9)  * N_NODES * 2);
  const float2* x1 = (const float2*)(X + (size_t)(b * TT + 10) * N_NODES * 2);
  const float2* x2 = (const float2*)(X + (size_t)(b * TT + 11) * N_NODES * 2);
  float a0x = 0.f, a0y = 0.f, a1x = 0.f, a1y = 0.f, a2x = 0.f, a2y = 0.f;
  int e0 = rp[n], e1 = rp[n + 1];
  for (int idx = e0 + lane; idx < e1; idx += 64) {
    float w = cnorm[idx];
    int s = csrc[idx];
    float2 s0 = x0[s], s1 = x1[s], s2v = x2[s];
    a0x += w * s0.x;  a0y += w * s0.y;
    a1x += w * s1.x;  a1y += w * s1.y;
    a2x += w * s2v.x; a2y += w * s2v.y;
  }
  if (lane == 0) {  // self-loop term
    float di = dinv[n];
    float sd = di * di;
    float2 v0 = x0[n], v1 = x1[n], v2 = x2[n];
    a0x += sd * v0.x; a0y += sd * v0.y;
    a1x += sd * v1.x; a1y += sd * v1.y;
    a2x += sd * v2.x; a2y += sd * v2.y;
  }
  #pragma unroll
  for (int off = 32; off > 0; off >>= 1) {
    a0x += __shfl_xor(a0x, off, 64);
    a0y += __shfl_xor(a0y, off, 64);
    a1x += __shfl_xor(a1x, off, 64);
    a1y += __shfl_xor(a1y, off, 64);
    a2x += __shfl_xor(a2x, off, 64);
    a2y += __shfl_xor(a2y, off, 64);
  }
  int c = lane;
  float w0 = W1[c], w1 = W1[64 + c], bc = b1[c];
  size_t ob = ((size_t)(b * N_NODES + n)) * 192 + c;
  h1[ob]       = fmaxf(a0x * w0 + a0y * w1 + bc, 0.0f);
  h1[ob + 64]  = fmaxf(a1x * w0 + a1y * w1 + bc, 0.0f);
  h1[ob + 128] = fmaxf(a2x * w0 + a2y * w1 + bc, 0.0f);
}

// ---------------- GCN layer 2 aggregation v3: wave per node, lane = channel ----------------
// Edge (src,w) bulk-loaded into lane registers once per 64-edge chunk, then broadcast per
// edge via v_readlane (uniform loop index -> SGPR, no DS pipe, no cross-lane reduce).
// t3 handled as 3 register passes over the same edge registers -> per-(b,t3) gather slice
// stays 2.56 MB (L2-resident per XCD via b = blockIdx&7 affinity).
__global__ __launch_bounds__(256) void k_agg3s(const float* __restrict__ h1,
                                               const float* __restrict__ dinv,
                                               const int* __restrict__ rp,
                                               const int* __restrict__ csrc,
                                               const float* __restrict__ cnorm,
                                               float* __restrict__ ah) {
  int b = blockIdx.x & 7;
  int grp = blockIdx.x >> 3;                 // 0..2499
  int n = grp * 4 + (threadIdx.x >> 6);
  int c = threadIdx.x & 63;
  const float* hb = h1 + (size_t)b * N_NODES * 192;
  float acc0 = 0.f, acc1 = 0.f, acc2 = 0.f;
  int e0 = rp[n], e1 = rp[n + 1];
  for (int base = e0; base < e1; base += 64) {
    int idx = base + c;
    int ic = (idx < e1) ? idx : e0;
    int sv = csrc[ic] * 192;                 // float offset of source node's 192-row
    float wf = (idx < e1) ? cnorm[idx] : 0.0f;
    int wb = __float_as_int(wf);
    int m = e1 - base; if (m > 64) m = 64;   // multiple of 8
    // pass t3 = 0
    {
      const float* pl = hb;                  // plane base (+ off uniform, + c per lane)
      for (int e = 0; e < m; e += 8) {
        #pragma unroll
        for (int u = 0; u < 8; u++) {
          int   off = __builtin_amdgcn_readlane(sv, e + u);
          float w   = __int_as_float(__builtin_amdgcn_readlane(wb, e + u));
          acc0 += w * (pl + off)[c];
        }
      }
    }
    // pass t3 = 1
    {
      const float* pl = hb + 64;
      for (int e = 0; e < m; e += 8) {
        #pragma unroll
        for (int u = 0; u < 8; u++) {
          int   off = __builtin_amdgcn_readlane(sv, e + u);
          float w   = __int_as_float(__builtin_amdgcn_readlane(wb, e + u));
          acc1 += w * (pl + off)[c];
        }
      }
    }
    // pass t3 = 2
    {
      const float* pl = hb + 128;
      for (int e = 0; e < m; e += 8) {
        #pragma unroll
        for (int u = 0; u < 8; u++) {
          int   off = __builtin_amdgcn_readlane(sv, e + u);
          float w   = __int_as_float(__builtin_amdgcn_readlane(wb, e + u));
          acc2 += w * (pl + off)[c];
        }
      }
    }
  }
  float di = dinv[n];
  float s2 = di * di;
  const float* selfr = hb + (size_t)n * 192;
  size_t ob = ((size_t)(b * N_NODES + n)) * 192 + c;
  ah[ob]       = acc0 + s2 * selfr[c];
  ah[ob + 64]  = acc1 + s2 * selfr[64 + c];
  ah[ob + 128] = acc2 + s2 * selfr[128 + c];
}

// ---------------- fused epilogue v2 (R5, measured 132 us): 32 nodes/block ----------------
// LDS 50,176 B -> 3 blocks/CU. Row-major [m][k] tiles with strides 36/196/132;
// all inner-loop LDS reads are float4 along k (b128), A-fragment reads are 2-4-address
// wave broadcasts -> no bank conflicts in the hot loops.
__global__ __launch_bounds__(256, 3) void k_fused(const float* __restrict__ ah,
                                                  const float* __restrict__ W2,
                                                  const float* __restrict__ b2,
                                                  const float* __restrict__ p1c,
                                                  const float* __restrict__ pb1,
                                                  const float* __restrict__ p2c,
                                                  const float* __restrict__ tc2b,
                                                  const float* __restrict__ ow,
                                                  const float* __restrict__ obp,
                                                  float* __restrict__ out) {
  __shared__ __align__(16) float smem[12544];    // 50,176 B
  float* spL = smem;                             // [32][196] = 6272
  float* ovl = smem + 6272;                      // As [96][36]=3456  |  t1L [32][132]=4224
  float* Ws  = smem + 6272 + 4224;               // 2048 floats (8 KB), shared chunk buffer
  float* As  = ovl;
  float* t1L = ovl;
  int tid = threadIdx.x;
  size_t nodeBase = (size_t)blockIdx.x * 32;     // in (b*N+n) units
  const float* A = ah + nodeBase * 192;          // 96 rows (n,t3) x 64, row-major

  // ---- phase 1: sp = relu(A[96x64] @ W2[64x64] + b2) -> spL[n][t3*64+c]
  {
    int ty = tid >> 4, tx = tid & 15;            // rows 6ty+i, cols 4tx+j
    float acc[6][4] = {{0.f}};
    for (int k0 = 0; k0 < 64; k0 += 32) {
      #pragma unroll
      for (int rep = 0; rep < 3; rep++) {        // As: 768 float4
        int idx = rep * 256 + tid;
        int m = idx >> 3, q4 = (idx & 7) * 4;
        *(float4*)&As[m * 36 + q4] = *(const float4*)(A + m * 64 + k0 + q4);
      }
      #pragma unroll
      for (int rep = 0; rep < 2; rep++) {        // Ws: [32][64] chunk of W2
        int idx = rep * 256 + tid;
        int kk = idx >> 4, c4 = (idx & 15) * 4;
        *(float4*)&Ws[kk * 64 + c4] = *(const float4*)(W2 + (size_t)(k0 + kk) * 64 + c4);
      }
      __syncthreads();
      #pragma unroll
      for (int k = 0; k < 32; k += 4) {
        float4 a[6], w[4];
        #pragma unroll
        for (int i = 0; i < 6; i++) a[i] = *(const float4*)&As[(6 * ty + i) * 36 + k];
        #pragma unroll
        for (int kk = 0; kk < 4; kk++) w[kk] = *(const float4*)&Ws[(k + kk) * 64 + 4 * tx];
        #pragma unroll
        for (int i = 0; i < 6; i++) {
          float av[4] = {a[i].x, a[i].y, a[i].z, a[i].w};
          #pragma unroll
          for (int kk = 0; kk < 4; kk++) {
            acc[i][0] += av[kk] * w[kk].x;
            acc[i][1] += av[kk] * w[kk].y;
            acc[i][2] += av[kk] * w[kk].z;
            acc[i][3] += av[kk] * w[kk].w;
          }
        }
      }
      __syncthreads();
    }
    float4 bv = *(const float4*)(b2 + 4 * tx);
    #pragma unroll
    for (int i = 0; i < 6; i++) {
      int m = 6 * ty + i;
      int n = m / 3, t3 = m % 3;
      float4 o;
      o.x = fmaxf(acc[i][0] + bv.x, 0.0f);
      o.y = fmaxf(acc[i][1] + bv.y, 0.0f);
      o.z = fmaxf(acc[i][2] + bv.z, 0.0f);
      o.w = fmaxf(acc[i][3] + bv.w, 0.0f);
      *(float4*)&spL[n * 196 + t3 * 64 + 4 * tx] = o;
    }
  }
  __syncthreads();

  // ---- phase 2: t1 = relu(spL[32x192] @ p1c[192x128] + pb1) -> t1L[32][132]
  {
    int ty = tid >> 5, tx = tid & 31;            // rows 4ty+i, cols 4tx+j
    float acc[4][4] = {{0.f}};
    for (int c12 = 0; c12 < 12; c12++) {
      #pragma unroll
      for (int rep = 0; rep < 2; rep++) {        // Ws: [16][128] chunk of p1c
        int idx = rep * 256 + tid;
        int kk = idx >> 5, c4 = (idx & 31) * 4;
        *(float4*)&Ws[kk * 128 + c4] = *(const float4*)(p1c + (size_t)(c12 * 16 + kk) * 128 + c4);
      }
      __syncthreads();
      int kbase = c12 * 16;
      #pragma unroll
      for (int k = 0; k < 16; k += 4) {
        float4 a[4], w[4];
        #pragma unroll
        for (int i = 0; i < 4; i++) a[i] = *(const float4*)&spL[(4 * ty + i) * 196 + kbase + k];
        #pragma unroll
        for (int kk = 0; kk < 4; kk++) w[kk] = *(const float4*)&Ws[(k + kk) * 128 + 4 * tx];
        #pragma unroll
        for (int i = 0; i < 4; i++) {
          float av[4] = {a[i].x, a[i].y, a[i].z, a[i].w};
          #pragma unroll
          for (int kk = 0; kk < 4; kk++) {
            acc[i][0] += av[kk] * w[kk].x;
            acc[i][1] += av[kk] * w[kk].y;
            acc[i][2] += av[kk] * w[kk].z;
            acc[i][3] += av[kk] * w[kk].w;
          }
        }
      }
      __syncthreads();
    }
    float4 bv = *(const float4*)(pb1 + 4 * tx);
    #pragma unroll
    for (int i = 0; i < 4; i++) {
      float4 o;
      o.x = fmaxf(acc[i][0] + bv.x, 0.0f);
      o.y = fmaxf(acc[i][1] + bv.y, 0.0f);
      o.z = fmaxf(acc[i][2] + bv.z, 0.0f);
      o.w = fmaxf(acc[i][3] + bv.w, 0.0f);
      *(float4*)&t1L[(4 * ty + i) * 132 + 4 * tx] = o;
    }
  }
  __syncthreads();

  // ---- phase 3: last = relu(t1L[32x128] @ p2c[128x64] + tc2b); out = last . ow + ob
  {
    int ty = tid >> 4, tx = tid & 15;            // rows 2ty+i, cols 4tx+j
    float acc[2][4] = {{0.f}};
    for (int c8 = 0; c8 < 8; c8++) {
      {                                          // Ws: [16][64] chunk of p2c
        int kk = tid >> 4, c4 = (tid & 15) * 4;
        *(float4*)&Ws[kk * 64 + c4] = *(const float4*)(p2c + (size_t)(c8 * 16 + kk) * 64 + c4);
      }
      __syncthreads();
      int kbase = c8 * 16;
      #pragma unroll
      for (int k = 0; k < 16; k += 4) {
        float4 a[2], w[4];
        #pragma unroll
        for (int i = 0; i < 2; i++) a[i] = *(const float4*)&t1L[(2 * ty + i) * 132 + kbase + k];
        #pragma unroll
        for (int kk = 0; kk < 4; kk++) w[kk] = *(const float4*)&Ws[(k + kk) * 64 + 4 * tx];
        #pragma unroll
        for (int i = 0; i < 2; i++) {
          float av[4] = {a[i].x, a[i].y, a[i].z, a[i].w};
          #pragma unroll
          for (int kk = 0; kk < 4; kk++) {
            acc[i][0] += av[kk] * w[kk].x;
            acc[i][1] += av[kk] * w[kk].y;
            acc[i][2] += av[kk] * w[kk].z;
            acc[i][3] += av[kk] * w[kk].w;
          }
        }
      }
      __syncthreads();
    }
    float4 bv = *(const float4*)(tc2b + 4 * tx);
    float4 o4 = *(const float4*)(ow + 4 * tx);
    float obv = obp[0];
    #pragma unroll
    for (int i = 0; i < 2; i++) {
      float v = fmaxf(acc[i][0] + bv.x, 0.0f) * o4.x
              + fmaxf(acc[i][1] + bv.y, 0.0f) * o4.y
              + fmaxf(acc[i][2] + bv.z, 0.0f) * o4.z
              + fmaxf(acc[i][3] + bv.w, 0.0f) * o4.w;
      v += __shfl_xor(v, 1, 64);
      v += __shfl_xor(v, 2, 64);
      v += __shfl_xor(v, 4, 64);
      v += __shfl_xor(v, 8, 64);
      if (tx == 0) out[nodeBase + 2 * ty + i] = v + obv;
    }
  }
}

// ---------------- launch ----------------

extern "C" void kernel_launch(void* const* d_in, const int* in_sizes, int n_in,
                              void* d_out, int out_size, void* d_ws, size_t ws_size,
                              hipStream_t stream) {
  const float* X    = (const float*)d_in[0];
  const int*   EI   = (const int*)  d_in[1];
  const float* EW   = (const float*)d_in[2];
  const float* W1   = (const float*)d_in[3];
  const float* B1   = (const float*)d_in[4];
  const float* W2   = (const float*)d_in[5];
  const float* B2   = (const float*)d_in[6];
  const float* TC1W = (const float*)d_in[7];
  const float* TC1B = (const float*)d_in[8];
  const float* TC2W = (const float*)d_in[9];
  const float* TC2B = (const float*)d_in[10];
  const float* OW   = (const float*)d_in[11];
  const float* OB   = (const float*)d_in[12];
  float* out = (float*)d_out;

  char* base = (char*)d_ws;
  size_t off = 0;
  auto alloc = [&](size_t bytes) -> char* {
    char* p = base + off;
    off += (bytes + 255) & ~(size_t)255;
    return p;
  };
  float* dinv  = (float*)alloc(N_NODES * 4);
  int*   cnt   = (int*)  alloc(N_NODES * 4);
  int*   rp    = (int*)  alloc((N_NODES + 1) * 4);
  int*   cur   = (int*)  alloc(N_NODES * 4);
  int*   csrc  = (int*)  alloc(EPAD * 4);
  float* cnorm = (float*)alloc(EPAD * 4);
  float* p1c   = (float*)alloc(192 * 128 * 4);
  float* p2c   = (float*)alloc(128 * 64 * 4);
  float* pb1   = (float*)alloc(128 * 4);
  const size_t BIG = (size_t)80000 * 192;
  float* h1 = (float*)alloc(BIG * 4);
  float* ah = (float*)alloc(BIG * 4);

  hipMemsetAsync(cnt, 0, N_NODES * 4, stream);
  k_cnt<<<625, 256, 0, stream>>>(EI, cnt);
  k_scan<<<1, 1024, 0, stream>>>(cnt, rp, cur);
  k_fill<<<625, 256, 0, stream>>>(EI, EW, cur, csrc, cnorm);
  k_padfill<<<40, 256, 0, stream>>>(rp, cur, csrc, cnorm);
  k_degsum<<<2500, 256, 0, stream>>>(rp, cnorm, dinv);
  k_wnorm<<<2500, 256, 0, stream>>>(rp, csrc, dinv, cnorm);
  k_pack<<<129, 256, 0, stream>>>(TC1W, TC2W, TC1B, p1c, p2c, pb1);

  // layer 1 (agg + W1 + relu), t=9..11 fused
  k_aggg1<<<20000, 256, 0, stream>>>(X, dinv, rp, csrc, cnorm, W1, B1, h1);
  // layer 2 aggregation: wave/node, lane=channel, readlane broadcast, t3 passes
  k_agg3s<<<20000, 256, 0, stream>>>(h1, dinv, rp, csrc, cnorm, ah);
  // fused W2-GEMM + conv1 + conv2 + out (32 nodes/block, LDS-staged weights)
  k_fused<<<2500, 256, 0, stream>>>(ah, W2, B2, p1c, pb1, p2c, TC2B, OW, OB, out);
}